// Round 2
// baseline (328.606 us; speedup 1.0000x reference)
//
#include <hip/hip_runtime.h>
#include <math.h>

#define NN 4096
#define SS 64
#define DD 64
#define HH 256
#define FF 256
// chunk_size is fixed at 256 by setup_inputs(); 16 chunks.

__device__ __forceinline__ float waveReduce(float v) {
#pragma unroll
  for (int o = 32; o > 0; o >>= 1) v += __shfl_down(v, o, 64);
  return v;
}

// acc layout (doubles): 0=c_num 1=f_num 2=b_num 3=msum 4=sig_sum 5=loss1 6=loss2 7=loss4 8=block_count
__global__ void k_zero(double* __restrict__ acc) {
  if (threadIdx.x < 16) acc[threadIdx.x] = 0.0;
}

__global__ void k_scalar(const float* __restrict__ rgbs, const float* __restrict__ ray_mask,
                         const float* __restrict__ coarse, const float* __restrict__ fine,
                         const float* __restrict__ beta, const float* __restrict__ sig,
                         double* __restrict__ acc) {
  int tid = blockIdx.x * blockDim.x + threadIdx.x;  // 4096 threads
  float c = 0.f, f = 0.f, b = 0.f, m = 0.f, s = 0.f;
  if (tid < NN) {
    float mk = ray_mask[tid];
    float bt = beta[tid];
    float inv2b2 = 1.0f / (2.0f * bt * bt);
#pragma unroll
    for (int ch = 0; ch < 3; ++ch) {
      float r = rgbs[tid * 3 + ch];
      float dc = coarse[tid * 3 + ch] - r;
      float df = fine[tid * 3 + ch] - r;
      c += dc * dc * mk;
      f += df * df * inv2b2 * mk;
    }
    c *= 0.5f;
    b = logf(bt) * mk;
    m = mk;
  }
  for (int i = tid; i < NN * SS; i += NN) s += sig[i];
  c = waveReduce(c); f = waveReduce(f); b = waveReduce(b); m = waveReduce(m); s = waveReduce(s);
  if ((threadIdx.x & 63) == 0) {
    atomicAdd(&acc[0], (double)c);
    atomicAdd(&acc[1], (double)f);
    atomicAdd(&acc[2], (double)b);
    atomicAdd(&acc[3], (double)m);
    atomicAdd(&acc[4], (double)s);
  }
}

// feat[n][d] = sum_s pt[n][s][d] * w[n][s].  One wave per n, float4 loads.
__global__ void k_feat(const float* __restrict__ pt, const float* __restrict__ w,
                       float* __restrict__ feat) {
  int wave = (blockIdx.x * blockDim.x + threadIdx.x) >> 6;
  int lane = threadIdx.x & 63;
  if (wave >= NN) return;
  const float4* p4 = (const float4*)(pt + (size_t)wave * SS * DD);
  const float* wr = w + wave * SS;
  float a0 = 0.f, a1 = 0.f, a2 = 0.f, a3 = 0.f;
#pragma unroll
  for (int it = 0; it < 16; ++it) {
    float4 v = p4[it * 64 + lane];
    float ws = wr[it * 4 + (lane >> 4)];
    a0 += v.x * ws; a1 += v.y * ws; a2 += v.z * ws; a3 += v.w * ws;
  }
  // lanes l, l^16, l^32, l^48 share the same d-group (lane&15)
  a0 += __shfl_xor(a0, 16, 64); a1 += __shfl_xor(a1, 16, 64);
  a2 += __shfl_xor(a2, 16, 64); a3 += __shfl_xor(a3, 16, 64);
  a0 += __shfl_xor(a0, 32, 64); a1 += __shfl_xor(a1, 32, 64);
  a2 += __shfl_xor(a2, 32, 64); a3 += __shfl_xor(a3, 32, 64);
  if (lane < 16) {
    float4 o = make_float4(a0, a1, a2, a3);
    ((float4*)(feat + wave * DD))[lane] = o;
  }
}

// h[n][j] = relu( feat[n][:] @ W1[0:64][j] + scale_n * W1[64][j] ), 4 rows/block
__global__ void k_h(const float* __restrict__ feat, const float* __restrict__ scales,
                    const float* __restrict__ W1, float* __restrict__ h, int larger) {
  int j = threadIdx.x;
  int n0 = blockIdx.x * 4;
  __shared__ float sf[4][DD];
  __shared__ float ss[4];
  if (j < 64) ((float4*)sf)[j] = ((const float4*)(feat + n0 * DD))[j];
  if (j < 4) {
    float sc = scales[n0 + j];
    if (larger) sc = sc + fmaxf(0.f, 2.0f - sc) * 0.5f;
    ss[j] = sc;
  }
  __syncthreads();
  float a0 = 0.f, a1 = 0.f, a2 = 0.f, a3 = 0.f;
#pragma unroll 4
  for (int k = 0; k < DD; k += 4) {
    float w0 = W1[(k + 0) * HH + j];
    float w1 = W1[(k + 1) * HH + j];
    float w2 = W1[(k + 2) * HH + j];
    float w3 = W1[(k + 3) * HH + j];
    float4 s0 = *(const float4*)&sf[0][k];
    float4 s1 = *(const float4*)&sf[1][k];
    float4 s2 = *(const float4*)&sf[2][k];
    float4 s3 = *(const float4*)&sf[3][k];
    a0 += s0.x * w0 + s0.y * w1 + s0.z * w2 + s0.w * w3;
    a1 += s1.x * w0 + s1.y * w1 + s1.z * w2 + s1.w * w3;
    a2 += s2.x * w0 + s2.y * w1 + s2.z * w2 + s2.w * w3;
    a3 += s3.x * w0 + s3.y * w1 + s3.z * w2 + s3.w * w3;
  }
  float wl = W1[64 * HH + j];
  a0 += ss[0] * wl; a1 += ss[1] * wl; a2 += ss[2] * wl; a3 += ss[3] * wl;
  h[(n0 + 0) * HH + j] = fmaxf(a0, 0.f);
  h[(n0 + 1) * HH + j] = fmaxf(a1, 0.f);
  h[(n0 + 2) * HH + j] = fmaxf(a2, 0.f);
  h[(n0 + 3) * HH + j] = fmaxf(a3, 0.f);
}

// g = normalize(h @ W2); writes g (row-major), gT (col-major), sqn (row norm^2 after normalize)
__global__ void k_g(const float* __restrict__ h, const float* __restrict__ W2,
                    float* __restrict__ g, float* __restrict__ gT, float* __restrict__ sqn) {
  int f = threadIdx.x;
  int n0 = blockIdx.x * 8;
  __shared__ float sh[8][HH];
  __shared__ float ssq[8];
  // stage 8 h-rows (contiguous 2048 floats)
#pragma unroll
  for (int it = 0; it < 2; ++it)
    ((float4*)sh)[it * 256 + f] = ((const float4*)(h + n0 * HH))[it * 256 + f];
  if (f < 8) ssq[f] = 0.f;
  __syncthreads();
  float a[8];
#pragma unroll
  for (int r = 0; r < 8; ++r) a[r] = 0.f;
  for (int k = 0; k < HH; k += 4) {
    float w0 = W2[(k + 0) * FF + f];
    float w1 = W2[(k + 1) * FF + f];
    float w2 = W2[(k + 2) * FF + f];
    float w3 = W2[(k + 3) * FF + f];
#pragma unroll
    for (int r = 0; r < 8; ++r) {
      float4 s4 = *(const float4*)&sh[r][k];
      a[r] += s4.x * w0 + s4.y * w1 + s4.z * w2 + s4.w * w3;
    }
  }
#pragma unroll
  for (int r = 0; r < 8; ++r) {
    float s = waveReduce(a[r] * a[r]);
    if ((threadIdx.x & 63) == 0) atomicAdd(&ssq[r], s);
  }
  __syncthreads();
#pragma unroll
  for (int r = 0; r < 8; ++r) {
    float inv = 1.0f / (sqrtf(ssq[r]) + 1e-6f);
    a[r] *= inv;
    g[(n0 + r) * FF + f] = a[r];
  }
  if (f < 8) {
    float inv = 1.0f / (sqrtf(ssq[f]) + 1e-6f);
    sqn[n0 + f] = ssq[f] * inv * inv;
  }
  float4 v0 = make_float4(a[0], a[1], a[2], a[3]);
  float4 v1 = make_float4(a[4], a[5], a[6], a[7]);
  float4* dst = (float4*)(gT + (size_t)f * NN + n0);
  dst[0] = v0; dst[1] = v1;
}

// Per-chunk masked pairwise loss. block = (chunk c, i-group of 8). 4 waves = 4 j-tiles of 64.
__global__ void k_pair(const float* __restrict__ g, const float* __restrict__ gT,
                       const float* __restrict__ sqn, const int* __restrict__ labels,
                       const float* __restrict__ beta, double* __restrict__ acc, int pass) {
  int c = blockIdx.x >> 5;
  int ig = blockIdx.x & 31;
  int t = threadIdx.x >> 6;   // j-tile
  int lane = threadIdx.x & 63;
  int i0 = c * 256 + ig * 8;
  __shared__ float sgi[8][FF];
  __shared__ float ssqi[8];
  __shared__ int sli[8];
  __shared__ int sst[8];
  // stage 8 g_i rows (contiguous)
#pragma unroll
  for (int it = 0; it < 2; ++it)
    ((float4*)sgi)[it * 256 + threadIdx.x] = ((const float4*)(g + (size_t)i0 * FF))[it * 256 + threadIdx.x];
  if (threadIdx.x < 8) {
    int i = i0 + threadIdx.x;
    ssqi[threadIdx.x] = sqn[i];
    sli[threadIdx.x] = labels[i];
    sst[threadIdx.x] = beta[i] < 0.15f ? 1 : 0;
  }
  __syncthreads();

  float fl1 = 0.f, fl4 = 0.f, fcnt = 0.f;
  if (t * 64 + 63 >= ig * 8) {  // tile contains some j >= i_min
    int jl = t * 64 + lane;     // local j in chunk
    int jg = c * 256 + jl;
    const float* gtc = gT + jg;
    float accum[8];
#pragma unroll
    for (int r = 0; r < 8; ++r) accum[r] = 0.f;
    for (int k = 0; k < FF; k += 4) {
      float v0 = gtc[(size_t)(k + 0) * NN];
      float v1 = gtc[(size_t)(k + 1) * NN];
      float v2 = gtc[(size_t)(k + 2) * NN];
      float v3 = gtc[(size_t)(k + 3) * NN];
#pragma unroll
      for (int r = 0; r < 8; ++r) {
        float4 s4 = *(const float4*)&sgi[r][k];
        accum[r] += s4.x * v0 + s4.y * v1 + s4.z * v2 + s4.w * v3;
      }
    }
    int lj = labels[jg];
    float sqj = sqn[jg];
    int statj = beta[jg] < 0.15f ? 1 : 0;
#pragma unroll
    for (int r = 0; r < 8; ++r) {
      int il = ig * 8 + r;
      if (jl >= il) {
        int li = sli[r];
        if (li != -1 && lj != -1) {
          fcnt += 1.0f;
          int stat = sst[r] | statj;
          if (stat) {
            float d2 = ssqi[r] + sqj - 2.0f * accum[r];
            float d = sqrtf(fmaxf(d2, 1e-12f));
            if (li == lj) {
              if (jl != il) fl1 += d;
            } else {
              fl4 += fmaxf(0.f, 1.0f - d);
            }
          }
        }
      }
    }
  }
  fl1 = waveReduce(fl1);
  fl4 = waveReduce(fl4);
  fcnt = waveReduce(fcnt);
  if (lane == 0) {
    if (pass == 0) {
      atomicAdd(&acc[5], (double)fl1);
      atomicAdd(&acc[7], (double)fl4);
      atomicAdd(&acc[8], (double)fcnt);
    } else {
      atomicAdd(&acc[6], (double)fl1);
    }
  }
}

__global__ void k_final(const double* __restrict__ acc, float* __restrict__ out) {
  if (threadIdx.x == 0) {
    double msum = acc[3] + 1e-20;
    out[0] = (float)(acc[0] / msum);
    out[1] = (float)(acc[1] / msum);
    out[2] = (float)(3.0 + acc[2] / msum);
    out[3] = (float)(0.01 * acc[4] / (double)(NN * SS));
    out[4] = (float)((acc[5] + acc[6] + acc[7]) / acc[8]);
  }
}

extern "C" void kernel_launch(void* const* d_in, const int* in_sizes, int n_in,
                              void* d_out, int out_size, void* d_ws, size_t ws_size,
                              hipStream_t stream) {
  const float* rgbs      = (const float*)d_in[0];
  const float* ray_mask  = (const float*)d_in[1];
  const float* rgb_coarse= (const float*)d_in[2];
  const float* rgb_fine  = (const float*)d_in[3];
  const float* beta      = (const float*)d_in[4];
  const float* sig       = (const float*)d_in[5];
  const float* pt        = (const float*)d_in[6];
  const float* wfs       = (const float*)d_in[7];
  const float* scales    = (const float*)d_in[8];
  const float* W1        = (const float*)d_in[9];
  const float* W2        = (const float*)d_in[10];
  const int*   labels    = (const int*)d_in[11];
  float* out = (float*)d_out;

  char* w = (char*)d_ws;
  double* acc = (double*)w;            // 16 doubles
  float* feat = (float*)(w + 256);     // N*64
  float* h    = feat + NN * DD;        // N*256
  float* g    = h + NN * HH;           // N*256
  float* gT   = g + NN * FF;           // N*256
  float* sqn  = gT + NN * FF;          // N

  k_zero<<<1, 64, 0, stream>>>(acc);
  k_scalar<<<16, 256, 0, stream>>>(rgbs, ray_mask, rgb_coarse, rgb_fine, beta, sig, acc);
  k_feat<<<1024, 256, 0, stream>>>(pt, wfs, feat);

  // pass 0: original scales -> loss1, loss4, block count
  k_h<<<1024, 256, 0, stream>>>(feat, scales, W1, h, 0);
  k_g<<<512, 256, 0, stream>>>(h, W2, g, gT, sqn);
  k_pair<<<512, 256, 0, stream>>>(g, gT, sqn, labels, beta, acc, 0);

  // pass 1: larger scales -> loss2
  k_h<<<1024, 256, 0, stream>>>(feat, scales, W1, h, 1);
  k_g<<<512, 256, 0, stream>>>(h, W2, g, gT, sqn);
  k_pair<<<512, 256, 0, stream>>>(g, gT, sqn, labels, beta, acc, 1);

  k_final<<<1, 64, 0, stream>>>(acc, out);
}